// Round 8
// baseline (57.927 us; speedup 1.0000x reference)
//
#include <hip/hip_runtime.h>

// GaussianAntecedent: out[n,r] = mem[n,r] / (sum_r mem[n,r] + 1e-8)
// mem = exp2( sum_d max( -(q*x + pn)^2 , L ) ),
//   q = sqrt(0.5*log2 e)/(sigma+eps), pn = -c*q, L = log2(1e-8) < 0
//
// R7 post-mortem: VGPR=48 proves the compiler REMATERIALIZES the q/pn
// computation (32 f32 divides ~250 instrs) per pair-iteration instead of
// holding 64 VGPRs of constants. RPW=4 quadrupled that cost (busy-time
// 15.7us -> 28.6us). R8: precompute q/pn ONCE into d_ws with a setup
// kernel; main kernel loads them as 16 float4 VMEM loads (16KB,
// L1-resident chip-wide). Keeps RPW=4 (25000 waves, ~3 occupancy fills).

typedef float v2f __attribute__((ext_vector_type(2)));

constexpr int DDIM = 32;
constexpr int RR   = 64;
constexpr int RPW  = 4;   // rows per wave (N=100000 -> 25000 waves, no tail)
constexpr int WPB  = 4;   // waves per block

__device__ inline float fast_exp2(float x) {
#if __has_builtin(__builtin_amdgcn_exp2f)
    return __builtin_amdgcn_exp2f(x);
#else
    return exp2f(x);
#endif
}

template <int CTRL>
__device__ inline float dpp_add(float x) {
    int t = __builtin_amdgcn_update_dpp(0, __float_as_int(x), CTRL, 0xF, 0xF, true);
    return x + __int_as_float(t);
}

// Wave64 sum, result broadcast to all lanes via SGPR.
__device__ inline float wave_sum_bcast(float x) {
    x = dpp_add<0x111>(x);  // row_shr:1
    x = dpp_add<0x112>(x);  // row_shr:2
    x = dpp_add<0x114>(x);  // row_shr:4
    x = dpp_add<0x118>(x);  // row_shr:8
    x = dpp_add<0x142>(x);  // row_bcast:15
    x = dpp_add<0x143>(x);  // row_bcast:31
    return __int_as_float(__builtin_amdgcn_readlane(__float_as_int(x), 63));
}

// ---- setup: q/pn tables, run once per launch (deterministic) ----
__global__ void gauss_setup_kernel(const float* __restrict__ centers,
                                   const float* __restrict__ sigma,
                                   float* __restrict__ ws) {
    const float SQK = 0.84932180028801907f;   // sqrt(0.5 * log2(e))
    int idx = blockIdx.x * blockDim.x + threadIdx.x;
    if (idx < RR * DDIM) {
        float q = SQK / (sigma[idx] + 1e-8f);
        ws[idx] = q;
        ws[RR * DDIM + idx] = -centers[idx] * q;
    }
}

__global__ __launch_bounds__(256, 4) void gauss_antecedent_kernel(
    const float* __restrict__ X,
    const float* __restrict__ qtab,   // d_ws: [RR*DDIM] q then [RR*DDIM] pn
    float* __restrict__ out, int N)
{
    const int lane = threadIdx.x & 63;
    const int wid  = blockIdx.x * WPB + (threadIdx.x >> 6);
    const int row0 = wid * RPW;
    if (row0 >= N) return;

    const float LC = -26.575424759098897f;    // log2(1e-8)
    const v2f L2 = {LC, LC};

    // Per-lane (rule = lane) constants: plain loads, no divides.
    const float4* __restrict__ qv =
        reinterpret_cast<const float4*>(qtab + lane * DDIM);
    const float4* __restrict__ pv =
        reinterpret_cast<const float4*>(qtab + RR * DDIM + lane * DDIM);
    v2f q2[DDIM / 2], pn2[DDIM / 2];
    #pragma unroll
    for (int j = 0; j < 8; ++j) {
        float4 a = qv[j], b = pv[j];
        q2[2 * j]      = (v2f){a.x, a.y};
        q2[2 * j + 1]  = (v2f){a.z, a.w};
        pn2[2 * j]     = (v2f){b.x, b.y};
        pn2[2 * j + 1] = (v2f){b.z, b.w};
    }

    if (row0 + RPW <= N) {
        const int r0s = __builtin_amdgcn_readfirstlane(row0);
        const float4* __restrict__ xbase =
            reinterpret_cast<const float4*>(X + (size_t)r0s * DDIM);

        // prologue: first pair of rows; wave-uniform addr -> s_load path.
        float4 cur[16];
        #pragma unroll
        for (int j = 0; j < 16; ++j) cur[j] = xbase[j];

        #pragma unroll
        for (int p = 0; p < RPW / 2; ++p) {
            v2f Ba[2] = {{0.f, 0.f}, {0.f, 0.f}};
            v2f Bb[2] = {{0.f, 0.f}, {0.f, 0.f}};
            #pragma unroll
            for (int j = 0; j < 8; ++j) {
                float4 a = cur[j], b = cur[8 + j];
                v2f a0 = {a.x, a.y}, a1 = {a.z, a.w};
                v2f b0 = {b.x, b.y}, b1 = {b.z, b.w};
                v2f ta0 = __builtin_elementwise_fma(q2[2*j],   a0, pn2[2*j]);
                v2f ta1 = __builtin_elementwise_fma(q2[2*j+1], a1, pn2[2*j+1]);
                v2f tb0 = __builtin_elementwise_fma(q2[2*j],   b0, pn2[2*j]);
                v2f tb1 = __builtin_elementwise_fma(q2[2*j+1], b1, pn2[2*j+1]);
                // B = max(B - t*t, B + L)  (exact: B + max(-t^2, L))
                v2f ua0 = __builtin_elementwise_fma(ta0, -ta0, Ba[0]);
                v2f ua1 = __builtin_elementwise_fma(ta1, -ta1, Ba[1]);
                v2f ub0 = __builtin_elementwise_fma(tb0, -tb0, Bb[0]);
                v2f ub1 = __builtin_elementwise_fma(tb1, -tb1, Bb[1]);
                Ba[0] = __builtin_elementwise_max(ua0, Ba[0] + L2);
                Ba[1] = __builtin_elementwise_max(ua1, Ba[1] + L2);
                Bb[0] = __builtin_elementwise_max(ub0, Bb[0] + L2);
                Bb[1] = __builtin_elementwise_max(ub1, Bb[1] + L2);
            }

            // prefetch next pair before the epilogue
            float4 nxt[16];
            if (p < RPW / 2 - 1) {
                const float4* __restrict__ nb = xbase + (p + 1) * 16;
                #pragma unroll
                for (int j = 0; j < 16; ++j) nxt[j] = nb[j];
            }

            v2f sa = Ba[0] + Ba[1];
            v2f sb = Bb[0] + Bb[1];
            float ma = fast_exp2(sa.x + sa.y);
            float mb = fast_exp2(sb.x + sb.y);
            float Sa = wave_sum_bcast(ma);
            float Sb = wave_sum_bcast(mb);
            const size_t o = (size_t)(r0s + 2 * p) * RR + lane;
            out[o]      = ma * __builtin_amdgcn_rcpf(Sa + 1e-8f);
            out[o + RR] = mb * __builtin_amdgcn_rcpf(Sb + 1e-8f);

            if (p < RPW / 2 - 1) {
                #pragma unroll
                for (int j = 0; j < 16; ++j) cur[j] = nxt[j];
            }
        }
    } else {
        // tail path (not taken for N=100000)
        for (int n = row0; n < N; ++n) {
            const int ns = __builtin_amdgcn_readfirstlane(n);
            const float4* __restrict__ xr =
                reinterpret_cast<const float4*>(X + (size_t)ns * DDIM);
            v2f B[2] = {{0.f, 0.f}, {0.f, 0.f}};
            #pragma unroll
            for (int j = 0; j < 8; ++j) {
                float4 xj = xr[j];
                v2f a0 = {xj.x, xj.y}, a1 = {xj.z, xj.w};
                v2f t0 = __builtin_elementwise_fma(q2[2*j],   a0, pn2[2*j]);
                v2f t1 = __builtin_elementwise_fma(q2[2*j+1], a1, pn2[2*j+1]);
                v2f u0 = __builtin_elementwise_fma(t0, -t0, B[0]);
                v2f u1 = __builtin_elementwise_fma(t1, -t1, B[1]);
                B[0] = __builtin_elementwise_max(u0, B[0] + L2);
                B[1] = __builtin_elementwise_max(u1, B[1] + L2);
            }
            v2f s = B[0] + B[1];
            float mem = fast_exp2(s.x + s.y);
            float S = wave_sum_bcast(mem);
            out[(size_t)ns * RR + lane] = mem * __builtin_amdgcn_rcpf(S + 1e-8f);
        }
    }
}

extern "C" void kernel_launch(void* const* d_in, const int* in_sizes, int n_in,
                              void* d_out, int out_size, void* d_ws, size_t ws_size,
                              hipStream_t stream) {
    const float* X       = (const float*)d_in[0];
    const float* centers = (const float*)d_in[1];
    const float* sigma   = (const float*)d_in[2];
    float* out = (float*)d_out;
    float* ws  = (float*)d_ws;   // needs 2*64*32*4 = 16 KB

    const int N = in_sizes[0] / DDIM;  // 100000

    // 1) build q/pn tables (2048 elems)
    gauss_setup_kernel<<<(RR * DDIM + 255) / 256, 256, 0, stream>>>(
        centers, sigma, ws);

    // 2) main kernel
    const int nwaves = (N + RPW - 1) / RPW;
    const int grid = (nwaves + WPB - 1) / WPB;
    gauss_antecedent_kernel<<<grid, 256, 0, stream>>>(X, ws, out, N);
}

// Round 9
// 39.707 us; speedup vs baseline: 1.4589x; 1.4589x over previous
//
#include <hip/hip_runtime.h>

// GaussianAntecedent: out[n,r] = mem[n,r] / (sum_r mem[n,r] + 1e-8)
// mem = exp2( sum_d max( -(q*x + pn)^2 , L ) ),
//   q = sqrt(0.5*log2 e)/(sigma+eps), pn = -c*q, L = log2(1e-8) < 0
//
// R8 post-mortem: VGPR=48 (< the 64 needed for q2/pn2) proves the
// compiler reloads the constant tables per iteration instead of keeping
// them register-resident; VALUBusy 27% = exposed gather latency.
// R9: PIN q2/pn2 in VGPRs with an opaque asm "+v" touch (can't be
// rematerialized or reloaded), RPW=8 (12500 waves ~ 12/SIMD demand,
// prologue amortized over 8 rows). Rest unchanged: q/pn setup kernel,
// s_load X path with depth-1 prefetch, DPP wave reduce, coalesced stores.

typedef float v2f __attribute__((ext_vector_type(2)));

constexpr int DDIM = 32;
constexpr int RR   = 64;
constexpr int RPW  = 8;   // rows per wave (N=100000 -> 12500 waves, no tail)
constexpr int WPB  = 4;   // waves per block

__device__ inline float fast_exp2(float x) {
#if __has_builtin(__builtin_amdgcn_exp2f)
    return __builtin_amdgcn_exp2f(x);
#else
    return exp2f(x);
#endif
}

template <int CTRL>
__device__ inline float dpp_add(float x) {
    int t = __builtin_amdgcn_update_dpp(0, __float_as_int(x), CTRL, 0xF, 0xF, true);
    return x + __int_as_float(t);
}

// Wave64 sum, result broadcast to all lanes via SGPR.
__device__ inline float wave_sum_bcast(float x) {
    x = dpp_add<0x111>(x);  // row_shr:1
    x = dpp_add<0x112>(x);  // row_shr:2
    x = dpp_add<0x114>(x);  // row_shr:4
    x = dpp_add<0x118>(x);  // row_shr:8
    x = dpp_add<0x142>(x);  // row_bcast:15
    x = dpp_add<0x143>(x);  // row_bcast:31
    return __int_as_float(__builtin_amdgcn_readlane(__float_as_int(x), 63));
}

// ---- setup: q/pn tables, run once per launch (deterministic) ----
__global__ void gauss_setup_kernel(const float* __restrict__ centers,
                                   const float* __restrict__ sigma,
                                   float* __restrict__ ws) {
    const float SQK = 0.84932180028801907f;   // sqrt(0.5 * log2(e))
    int idx = blockIdx.x * blockDim.x + threadIdx.x;
    if (idx < RR * DDIM) {
        float q = SQK / (sigma[idx] + 1e-8f);
        ws[idx] = q;
        ws[RR * DDIM + idx] = -centers[idx] * q;
    }
}

__global__ __launch_bounds__(256, 4) void gauss_antecedent_kernel(
    const float* __restrict__ X,
    const float* __restrict__ qtab,   // d_ws: [RR*DDIM] q then [RR*DDIM] pn
    float* __restrict__ out, int N)
{
    const int lane = threadIdx.x & 63;
    const int wid  = blockIdx.x * WPB + (threadIdx.x >> 6);
    const int row0 = wid * RPW;
    if (row0 >= N) return;

    const float LC = -26.575424759098897f;    // log2(1e-8)
    const v2f L2 = {LC, LC};

    // Per-lane (rule = lane) constants: plain loads, no divides.
    const float4* __restrict__ qv =
        reinterpret_cast<const float4*>(qtab + lane * DDIM);
    const float4* __restrict__ pv =
        reinterpret_cast<const float4*>(qtab + RR * DDIM + lane * DDIM);
    v2f q2[DDIM / 2], pn2[DDIM / 2];
    #pragma unroll
    for (int j = 0; j < 8; ++j) {
        float4 a = qv[j], b = pv[j];
        q2[2 * j]      = (v2f){a.x, a.y};
        q2[2 * j + 1]  = (v2f){a.z, a.w};
        pn2[2 * j]     = (v2f){b.x, b.y};
        pn2[2 * j + 1] = (v2f){b.z, b.w};
    }
    // PIN the constants in VGPRs: opaque asm output cannot be
    // rematerialized or re-loaded; compiler must carry them in registers.
    #pragma unroll
    for (int j = 0; j < DDIM / 2; ++j) {
        asm volatile("" : "+v"(q2[j]), "+v"(pn2[j]));
    }

    if (row0 + RPW <= N) {
        const int r0s = __builtin_amdgcn_readfirstlane(row0);
        const float4* __restrict__ xbase =
            reinterpret_cast<const float4*>(X + (size_t)r0s * DDIM);

        // prologue: first pair of rows; wave-uniform addr -> s_load path.
        float4 cur[16];
        #pragma unroll
        for (int j = 0; j < 16; ++j) cur[j] = xbase[j];

        #pragma unroll
        for (int p = 0; p < RPW / 2; ++p) {
            v2f Ba[2] = {{0.f, 0.f}, {0.f, 0.f}};
            v2f Bb[2] = {{0.f, 0.f}, {0.f, 0.f}};
            #pragma unroll
            for (int j = 0; j < 8; ++j) {
                float4 a = cur[j], b = cur[8 + j];
                v2f a0 = {a.x, a.y}, a1 = {a.z, a.w};
                v2f b0 = {b.x, b.y}, b1 = {b.z, b.w};
                v2f ta0 = __builtin_elementwise_fma(q2[2*j],   a0, pn2[2*j]);
                v2f ta1 = __builtin_elementwise_fma(q2[2*j+1], a1, pn2[2*j+1]);
                v2f tb0 = __builtin_elementwise_fma(q2[2*j],   b0, pn2[2*j]);
                v2f tb1 = __builtin_elementwise_fma(q2[2*j+1], b1, pn2[2*j+1]);
                // B = max(B - t*t, B + L)  (exact: B + max(-t^2, L))
                v2f ua0 = __builtin_elementwise_fma(ta0, -ta0, Ba[0]);
                v2f ua1 = __builtin_elementwise_fma(ta1, -ta1, Ba[1]);
                v2f ub0 = __builtin_elementwise_fma(tb0, -tb0, Bb[0]);
                v2f ub1 = __builtin_elementwise_fma(tb1, -tb1, Bb[1]);
                Ba[0] = __builtin_elementwise_max(ua0, Ba[0] + L2);
                Ba[1] = __builtin_elementwise_max(ua1, Ba[1] + L2);
                Bb[0] = __builtin_elementwise_max(ub0, Bb[0] + L2);
                Bb[1] = __builtin_elementwise_max(ub1, Bb[1] + L2);
            }

            // prefetch next pair before the epilogue
            float4 nxt[16];
            if (p < RPW / 2 - 1) {
                const float4* __restrict__ nb = xbase + (p + 1) * 16;
                #pragma unroll
                for (int j = 0; j < 16; ++j) nxt[j] = nb[j];
            }

            v2f sa = Ba[0] + Ba[1];
            v2f sb = Bb[0] + Bb[1];
            float ma = fast_exp2(sa.x + sa.y);
            float mb = fast_exp2(sb.x + sb.y);
            float Sa = wave_sum_bcast(ma);
            float Sb = wave_sum_bcast(mb);
            const size_t o = (size_t)(r0s + 2 * p) * RR + lane;
            out[o]      = ma * __builtin_amdgcn_rcpf(Sa + 1e-8f);
            out[o + RR] = mb * __builtin_amdgcn_rcpf(Sb + 1e-8f);

            if (p < RPW / 2 - 1) {
                #pragma unroll
                for (int j = 0; j < 16; ++j) cur[j] = nxt[j];
            }
        }
    } else {
        // tail path (not taken for N=100000)
        for (int n = row0; n < N; ++n) {
            const int ns = __builtin_amdgcn_readfirstlane(n);
            const float4* __restrict__ xr =
                reinterpret_cast<const float4*>(X + (size_t)ns * DDIM);
            v2f B[2] = {{0.f, 0.f}, {0.f, 0.f}};
            #pragma unroll
            for (int j = 0; j < 8; ++j) {
                float4 xj = xr[j];
                v2f a0 = {xj.x, xj.y}, a1 = {xj.z, xj.w};
                v2f t0 = __builtin_elementwise_fma(q2[2*j],   a0, pn2[2*j]);
                v2f t1 = __builtin_elementwise_fma(q2[2*j+1], a1, pn2[2*j+1]);
                v2f u0 = __builtin_elementwise_fma(t0, -t0, B[0]);
                v2f u1 = __builtin_elementwise_fma(t1, -t1, B[1]);
                B[0] = __builtin_elementwise_max(u0, B[0] + L2);
                B[1] = __builtin_elementwise_max(u1, B[1] + L2);
            }
            v2f s = B[0] + B[1];
            float mem = fast_exp2(s.x + s.y);
            float S = wave_sum_bcast(mem);
            out[(size_t)ns * RR + lane] = mem * __builtin_amdgcn_rcpf(S + 1e-8f);
        }
    }
}

extern "C" void kernel_launch(void* const* d_in, const int* in_sizes, int n_in,
                              void* d_out, int out_size, void* d_ws, size_t ws_size,
                              hipStream_t stream) {
    const float* X       = (const float*)d_in[0];
    const float* centers = (const float*)d_in[1];
    const float* sigma   = (const float*)d_in[2];
    float* out = (float*)d_out;
    float* ws  = (float*)d_ws;   // needs 2*64*32*4 = 16 KB

    const int N = in_sizes[0] / DDIM;  // 100000

    // 1) build q/pn tables (2048 elems)
    gauss_setup_kernel<<<(RR * DDIM + 255) / 256, 256, 0, stream>>>(
        centers, sigma, ws);

    // 2) main kernel
    const int nwaves = (N + RPW - 1) / RPW;
    const int grid = (nwaves + WPB - 1) / WPB;
    gauss_antecedent_kernel<<<grid, 256, 0, stream>>>(X, ws, out, N);
}